// Round 16
// baseline (5644.189 us; speedup 1.0000x reference)
//
#include <hip/hip_runtime.h>
#include <hip/hip_bf16.h>

typedef __attribute__((ext_vector_type(8))) _Float16 half8;
typedef __attribute__((ext_vector_type(4))) _Float16 half4v;
typedef __attribute__((ext_vector_type(4))) float f32x4;
typedef __attribute__((ext_vector_type(2))) float f32x2;
typedef unsigned long long u64;

#define T_SEQ 512
#define N_B   64
#define D_IN  512
#define N_U   1024

// ---- workspace layout (bytes) ----
// hseq: one 64x1024 fp16 buffer PER TIMESTEP (513 slots). Producers publish via
// agent-scope atomicExch; readers use PLAIN cached loads (virgin address per step ->
// first read per XCD misses L2, hits MALL; other WGs hit shared L2).
// fseq: per-step per-CHAIN flag buffers [513][4][128] u32. The LSTM recurrence is
// independent per batch row; wave w of every WG touches ONLY rows 16w..16w+15, so
// the 4 waves form 4 independent recurrence chains. Each chain has its own flag set
// and syncs only with itself -> chains drift freely and overlap each other's
// fabric-latency windows. No per-step __syncthreads anywhere.
#define OFF_CNT   0ull                           /* legacy area, zeroed */
#define OFF_HSEQ  65536ull                       /* 513 x 131072 B */
#define OFF_XB    (OFF_HSEQ + 513ull*131072ull)  /* xb [512*64][512] fp16 = 32 MiB */
#define OFF_WBT   (OFF_XB + 33554432ull)         /* WbT [4096][512] fp16 = 4 MiB */
#define OFF_WHT   (OFF_WBT + 4194304ull)         /* WhT [4096][1024] fp16 = 8 MiB */
#define OFF_BIAS  (OFF_WHT + 8388608ull)         /* biasv [4096] f32 */
#define OFF_FSEQ  (OFF_BIAS + 16384ull)          /* fseq [513][4][128] u32 = 1050624 B */

__device__ __forceinline__ float sigf(float x) { return 1.f / (1.f + __expf(-x)); }
__device__ __forceinline__ float tanhfast(float x) { return 2.f / (1.f + __expf(-2.f * x)) - 1.f; }

// ---- pack x: xb[t*64+b][k] = fp16(x[b][t][k]) ----
__global__ __launch_bounds__(256) void pack_x(const float* __restrict__ x, _Float16* __restrict__ xb) {
  size_t i4 = ((size_t)blockIdx.x * 256 + threadIdx.x) * 4;
  int m = (int)(i4 >> 9), k = (int)(i4 & 511);
  int t = m >> 6, b = m & 63;
  const float4 v = *(const float4*)(x + ((size_t)b * T_SEQ + t) * D_IN + k);
  half4v o; o.x = (_Float16)v.x; o.y = (_Float16)v.y; o.z = (_Float16)v.z; o.w = (_Float16)v.w;
  *(half4v*)(xb + i4) = o;
}

// ---- pack W: WbT[n][k] (k<512) and WhT[n][k-512], n = u*4+g (f,i,o,c) ----
__global__ __launch_bounds__(256) void pack_w(const float* __restrict__ Wf, const float* __restrict__ Wi,
                                              const float* __restrict__ Wo, const float* __restrict__ Wc,
                                              _Float16* __restrict__ WbT, _Float16* __restrict__ WhT) {
  size_t i4 = ((size_t)blockIdx.x * 256 + threadIdx.x) * 4;
  int n = (int)(i4 / 1536), k = (int)(i4 % 1536);
  int g = n & 3, u = n >> 2;
  const float* W = (g == 0) ? Wf : (g == 1) ? Wi : (g == 2) ? Wo : Wc;
  half4v o;
  o.x = (_Float16)W[(size_t)(k + 0) * N_U + u];
  o.y = (_Float16)W[(size_t)(k + 1) * N_U + u];
  o.z = (_Float16)W[(size_t)(k + 2) * N_U + u];
  o.w = (_Float16)W[(size_t)(k + 3) * N_U + u];
  if (k < D_IN) *(half4v*)(WbT + (size_t)n * D_IN + k) = o;
  else          *(half4v*)(WhT + (size_t)n * N_U + (k - D_IN)) = o;
}

__global__ __launch_bounds__(256) void pack_b(const float* __restrict__ bf_, const float* __restrict__ bi_,
                                              const float* __restrict__ bo_, const float* __restrict__ bc_,
                                              float* __restrict__ biasv) {
  int n = blockIdx.x * 256 + threadIdx.x;
  int g = n & 3, u = n >> 2;
  biasv[n] = (g == 0) ? bf_[u] : (g == 1) ? bi_[u] : (g == 2) ? bo_[u] : bc_[u];
}

// 4x4 in-quad transpose via 2 butterfly stages of ds_swizzle (xor1, xor2).
__device__ __forceinline__ void quadtr(f32x4 v, int gg, float& F, float& I, float& O, float& G) {
  const bool o1 = gg & 1, o2 = gg & 2;
  float s01 = o1 ? v[0] : v[1];
  float s23 = o1 ? v[2] : v[3];
  float r01 = __int_as_float(__builtin_amdgcn_ds_swizzle(__float_as_int(s01), 0x041F)); // xor 1
  float r23 = __int_as_float(__builtin_amdgcn_ds_swizzle(__float_as_int(s23), 0x041F));
  float x0 = o1 ? r01 : v[0];
  float x1 = o1 ? v[1] : r01;
  float x2 = o1 ? r23 : v[2];
  float x3 = o1 ? v[3] : r23;
  float s02 = o2 ? x0 : x2;
  float s13 = o2 ? x1 : x3;
  float r02 = __int_as_float(__builtin_amdgcn_ds_swizzle(__float_as_int(s02), 0x081F)); // xor 2
  float r13 = __int_as_float(__builtin_amdgcn_ds_swizzle(__float_as_int(s13), 0x081F));
  F = o2 ? r02 : x0;
  I = o2 ? r13 : x1;
  O = o2 ? x2 : r02;
  G = o2 ? x3 : r13;
}

// ---- persistent recurrence. R11 compute structure; sync split into 4 INDEPENDENT
// per-wave chains (wave w of all 128 WGs = recurrence for batch rows 16w..16w+15).
// Per chain: plain-L2 flag detect (sc1 fallback), per-wave vmcnt(0) drain, lane-0
// flag exch. Chains drift freely; each chain's fabric-latency window is overlapped
// by the other 3 chains' compute on the same CU. (R13's decoupling failed because
// all waves shared ONE chain's flags — no drift was possible; here the chains are
// genuinely independent by the problem's dependency structure.)
__global__ __launch_bounds__(256, 1) void lstm_rec(
    const _Float16* __restrict__ xb, const _Float16* __restrict__ WbT,
    const _Float16* __restrict__ WhT, const float* __restrict__ biasv,
    _Float16* __restrict__ hseq, float* __restrict__ out, unsigned* __restrict__ fseq) {
  const int wg = blockIdx.x;           // 0..127
  const int tid = threadIdx.x;
  const int l = tid & 63, w = tid >> 6;
  const int lr = l & 15, lkb = (l >> 4) * 8;
  const int arow = w * 16 + lr;        // batch row this lane supplies to MFMA-A (chain w)
  const int uu = lr >> 2, gg = l & 3;  // quad id / quad member
  const int u0 = wg * 8 + 2 * uu;      // lane's unit pair (after transpose)
  const int R  = w * 16 + (l >> 4) * 4 + gg;  // lane's batch row (after transpose, chain w)

  __shared__ half8 wlds[96 * 64];      // 96 KiB: slot = kk*2+nf; kk<16 -> W_x, else W_h

  for (int idx = tid; idx < 96 * 64; idx += 256) {
    int s = idx >> 6, l2 = idx & 63;
    int kk = s >> 1, nf = s & 1;
    int uu2 = (l2 & 15) >> 2, gg2 = l2 & 3, lkb2 = (l2 >> 4) * 8;
    int col = (wg * 8 + 2 * uu2 + nf) * 4 + gg2;   // interleaved unit assignment
    const _Float16* src = (kk < 16)
      ? WbT + (size_t)col * D_IN + kk * 32 + lkb2
      : WhT + (size_t)col * N_U + (kk - 16) * 32 + lkb2;
    wlds[idx] = *(const half8*)src;
  }

  const float bv0 = biasv[(size_t)u0 * 4 + gg];
  const float bv1 = biasv[(size_t)(u0 + 1) * 4 + gg];
  float c0 = 0.f, c1 = 0.f;

  __syncthreads();                     // wlds ready (pre-loop only)

  // hoist h-part a-chain W fragments (j=0..15, both col-frags) into regs (R5-proven,
  // NO pin — R12's "+v" pin forced arch-VGPR allocation and cost 70%)
  half8 wh0[16], wh1[16];
#pragma unroll
  for (int j = 0; j < 16; j++) {
    wh0[j] = wlds[((16 + j) * 2 + 0) * 64 + l];
    wh1[j] = wlds[((16 + j) * 2 + 1) * 64 + l];
  }

  // ---- prologue: x-part of step 0 ----
  half8 xfn[16];
  {
    const _Float16* xa = xb + (size_t)arow * D_IN + lkb;
#pragma unroll
    for (int j = 0; j < 16; j++) xfn[j] = *(const half8*)(xa + j * 32);
  }
  f32x4 a0 = {bv0, bv0, bv0, bv0};
  f32x4 a1 = {bv1, bv1, bv1, bv1};
#pragma unroll
  for (int j = 0; j < 16; j++) {
    a0 = __builtin_amdgcn_mfma_f32_16x16x32_f16(xfn[j], wlds[(j * 2 + 0) * 64 + l], a0, 0, 0, 0);
    a1 = __builtin_amdgcn_mfma_f32_16x16x32_f16(xfn[j], wlds[(j * 2 + 1) * 64 + l], a1, 0, 0, 0);
  }

  for (int g = 0; g < T_SEQ; g++) {
    // ---- B: wait until all 128 WGs published CHAIN w of h_g (per-wave, no barrier) ----
    if (g > 0) {
      unsigned* fg = fseq + (size_t)g * 512 + (size_t)w * 128;
      unsigned v0 = *((volatile const unsigned*)fg + l);        // plain cached (L2)
      unsigned v1 = *((volatile const unsigned*)fg + 64 + l);
      if (v0 == 0u) {
        while (__hip_atomic_load(&fg[l], __ATOMIC_RELAXED, __HIP_MEMORY_SCOPE_AGENT) == 0u)
          __builtin_amdgcn_s_sleep(1);
      }
      if (v1 == 0u) {
        while (__hip_atomic_load(&fg[64 + l], __ATOMIC_RELAXED, __HIP_MEMORY_SCOPE_AGENT) == 0u)
          __builtin_amdgcn_s_sleep(1);
      }
      asm volatile("" ::: "memory");   // compiler fence: no hoisting of h loads
    }

    // ---- C: h loads (chain w rows, plain L2-shared) + next-step x loads + 64 h-MFMAs ----
    const _Float16* hp = hseq + (size_t)g * (N_B * N_U) + (size_t)arow * N_U + lkb;
    half8 hf[32];
#pragma unroll
    for (int j = 0; j < 32; j++) hf[j] = *(const half8*)(hp + j * 32);

    const int gn = (g + 1 < T_SEQ) ? g + 1 : 0;
    const _Float16* xa = xb + ((size_t)gn * N_B + arow) * D_IN + lkb;
#pragma unroll
    for (int j = 0; j < 16; j++) xfn[j] = *(const half8*)(xa + j * 32);

    f32x4 b0 = {0.f, 0.f, 0.f, 0.f};
    f32x4 b1 = {0.f, 0.f, 0.f, 0.f};
#pragma unroll
    for (int j = 0; j < 16; j++) {
      a0 = __builtin_amdgcn_mfma_f32_16x16x32_f16(hf[j],      wh0[j], a0, 0, 0, 0);
      a1 = __builtin_amdgcn_mfma_f32_16x16x32_f16(hf[j],      wh1[j], a1, 0, 0, 0);
      b0 = __builtin_amdgcn_mfma_f32_16x16x32_f16(hf[j + 16], wlds[((32 + j) * 2 + 0) * 64 + l], b0, 0, 0, 0);
      b1 = __builtin_amdgcn_mfma_f32_16x16x32_f16(hf[j + 16], wlds[((32 + j) * 2 + 1) * 64 + l], b1, 0, 0, 0);
    }
    a0 += b0;
    a1 += b1;

    // ---- D: in-wave quad transpose + elementwise ----
    float F0, I0, O0, G0, F1, I1, O1, G1;
    quadtr(a0, gg, F0, I0, O0, G0);
    quadtr(a1, gg, F1, I1, O1, G1);
    c0 = sigf(F0) * c0 + sigf(I0) * tanhfast(G0);
    c1 = sigf(F1) * c1 + sigf(I1) * tanhfast(G1);
    float h0v = sigf(O0) * tanhfast(c0);
    float h1v = sigf(O1) * tanhfast(c1);

    // ---- E: publish h_{g+1} — one packed 4B agent atomicExch per lane ----
    unsigned hw;
    { union { _Float16 h[2]; unsigned u; } pk; pk.h[0] = (_Float16)h0v; pk.h[1] = (_Float16)h1v; hw = pk.u; }
    unsigned* hn = (unsigned*)(hseq + (size_t)(g + 1) * (N_B * N_U) + (size_t)R * N_U + u0);
    (void)__hip_atomic_exchange(hn, hw, __ATOMIC_RELAXED, __HIP_MEMORY_SCOPE_AGENT);

    // ---- A1: first half of next step's x-GEMM (covers the publish-ack drain) ----
    a0 = f32x4{bv0, bv0, bv0, bv0};
    a1 = f32x4{bv1, bv1, bv1, bv1};
#pragma unroll
    for (int j = 0; j < 8; j++) {
      a0 = __builtin_amdgcn_mfma_f32_16x16x32_f16(xfn[j], wlds[(j * 2 + 0) * 64 + l], a0, 0, 0, 0);
      a1 = __builtin_amdgcn_mfma_f32_16x16x32_f16(xfn[j], wlds[(j * 2 + 1) * 64 + l], a1, 0, 0, 0);
    }

    // ---- F: per-wave drain (own exchs acked at MALL) + lane-0 chain-flag publish ----
    asm volatile("s_waitcnt vmcnt(0)" ::: "memory");
    if (l == 0)
      (void)__hip_atomic_exchange(&fseq[(size_t)(g + 1) * 512 + (size_t)w * 128 + wg], 1u,
                                  __ATOMIC_RELAXED, __HIP_MEMORY_SCOPE_AGENT);

    // ---- A2: second half of next step's x-GEMM (covers flag propagation) ----
#pragma unroll
    for (int j = 8; j < 16; j++) {
      a0 = __builtin_amdgcn_mfma_f32_16x16x32_f16(xfn[j], wlds[(j * 2 + 0) * 64 + l], a0, 0, 0, 0);
      a1 = __builtin_amdgcn_mfma_f32_16x16x32_f16(xfn[j], wlds[(j * 2 + 1) * 64 + l], a1, 0, 0, 0);
    }

    // ---- G: out store (nt), off the release path ----
    f32x2 ov; ov.x = h0v; ov.y = h1v;
    __builtin_nontemporal_store(ov, (f32x2*)(out + ((size_t)R * T_SEQ + g) * N_U + u0));
  }
}

extern "C" void kernel_launch(void* const* d_in, const int* in_sizes, int n_in,
                              void* d_out, int out_size, void* d_ws, size_t ws_size,
                              hipStream_t stream) {
  const float* x  = (const float*)d_in[0];
  const float* Wf = (const float*)d_in[1];
  const float* Wi = (const float*)d_in[2];
  const float* Wo = (const float*)d_in[3];
  const float* Wc = (const float*)d_in[4];
  const float* bf_ = (const float*)d_in[5];
  const float* bi_ = (const float*)d_in[6];
  const float* bo_ = (const float*)d_in[7];
  const float* bc_ = (const float*)d_in[8];
  float* out = (float*)d_out;

  char* ws = (char*)d_ws;
  _Float16* hseq = (_Float16*)(ws + OFF_HSEQ);
  _Float16* xb   = (_Float16*)(ws + OFF_XB);
  _Float16* WbT  = (_Float16*)(ws + OFF_WBT);
  _Float16* WhT  = (_Float16*)(ws + OFF_WHT);
  float* biasv = (float*)(ws + OFF_BIAS);
  unsigned* fseq = (unsigned*)(ws + OFF_FSEQ);

  (void)hipMemsetAsync(d_ws, 0, 1 << 20, stream);                // hseq[0] (h_0 = zeros)
  (void)hipMemsetAsync(ws + OFF_FSEQ, 0, 513 * 2048, stream);    // per-step per-chain flags
  pack_x<<<16384, 256, 0, stream>>>(x, xb);
  pack_w<<<6144, 256, 0, stream>>>(Wf, Wi, Wo, Wc, WbT, WhT);
  pack_b<<<16, 256, 0, stream>>>(bf_, bi_, bo_, bc_, biasv);

  lstm_rec<<<128, 256, 0, stream>>>(xb, WbT, WhT, biasv, hseq, out, fseq);
}

// Round 17
// 3139.788 us; speedup vs baseline: 1.7976x; 1.7976x over previous
//
#include <hip/hip_runtime.h>
#include <hip/hip_bf16.h>

typedef __attribute__((ext_vector_type(8))) _Float16 half8;
typedef __attribute__((ext_vector_type(4))) _Float16 half4v;
typedef __attribute__((ext_vector_type(4))) float f32x4;
typedef __attribute__((ext_vector_type(2))) float f32x2;
typedef unsigned long long u64;

#define T_SEQ 512
#define N_B   64
#define D_IN  512
#define N_U   1024

// ---- workspace layout (bytes) ----
// hseq: one 64x1024 fp16 buffer PER TIMESTEP (513 slots). Producers publish via
// agent-scope atomicExch; readers use PLAIN cached loads (virgin address per step ->
// first read per XCD misses L2, hits MALL; other WGs hit shared L2).
// fseq: per-step flag buffers [513][128] u32 -> PLAIN cached flag reads (L2-local),
// sc1 fallback only when a lane reads 0.
#define OFF_CNT   0ull                           /* legacy flag area (unused), zeroed */
#define OFF_HSEQ  65536ull                       /* 513 x 131072 B */
#define OFF_XB    (OFF_HSEQ + 513ull*131072ull)  /* xb [512*64][512] fp16 = 32 MiB */
#define OFF_WBT   (OFF_XB + 33554432ull)         /* WbT [4096][512] fp16 = 4 MiB */
#define OFF_WHT   (OFF_WBT + 4194304ull)         /* WhT [4096][1024] fp16 = 8 MiB */
#define OFF_BIAS  (OFF_WHT + 8388608ull)         /* biasv [4096] f32 */
#define OFF_FSEQ  (OFF_BIAS + 16384ull)          /* fseq [513][128] u32 = 262656 B */

__device__ __forceinline__ float sigf(float x) { return 1.f / (1.f + __expf(-x)); }
__device__ __forceinline__ float tanhfast(float x) { return 2.f / (1.f + __expf(-2.f * x)) - 1.f; }

// ---- pack x: xb[t*64+b][k] = fp16(x[b][t][k]) ----
__global__ __launch_bounds__(256) void pack_x(const float* __restrict__ x, _Float16* __restrict__ xb) {
  size_t i4 = ((size_t)blockIdx.x * 256 + threadIdx.x) * 4;
  int m = (int)(i4 >> 9), k = (int)(i4 & 511);
  int t = m >> 6, b = m & 63;
  const float4 v = *(const float4*)(x + ((size_t)b * T_SEQ + t) * D_IN + k);
  half4v o; o.x = (_Float16)v.x; o.y = (_Float16)v.y; o.z = (_Float16)v.z; o.w = (_Float16)v.w;
  *(half4v*)(xb + i4) = o;
}

// ---- pack W: WbT[n][k] (k<512) and WhT[n][k-512], n = u*4+g (f,i,o,c) ----
__global__ __launch_bounds__(256) void pack_w(const float* __restrict__ Wf, const float* __restrict__ Wi,
                                              const float* __restrict__ Wo, const float* __restrict__ Wc,
                                              _Float16* __restrict__ WbT, _Float16* __restrict__ WhT) {
  size_t i4 = ((size_t)blockIdx.x * 256 + threadIdx.x) * 4;
  int n = (int)(i4 / 1536), k = (int)(i4 % 1536);
  int g = n & 3, u = n >> 2;
  const float* W = (g == 0) ? Wf : (g == 1) ? Wi : (g == 2) ? Wo : Wc;
  half4v o;
  o.x = (_Float16)W[(size_t)(k + 0) * N_U + u];
  o.y = (_Float16)W[(size_t)(k + 1) * N_U + u];
  o.z = (_Float16)W[(size_t)(k + 2) * N_U + u];
  o.w = (_Float16)W[(size_t)(k + 3) * N_U + u];
  if (k < D_IN) *(half4v*)(WbT + (size_t)n * D_IN + k) = o;
  else          *(half4v*)(WhT + (size_t)n * N_U + (k - D_IN)) = o;
}

__global__ __launch_bounds__(256) void pack_b(const float* __restrict__ bf_, const float* __restrict__ bi_,
                                              const float* __restrict__ bo_, const float* __restrict__ bc_,
                                              float* __restrict__ biasv) {
  int n = blockIdx.x * 256 + threadIdx.x;
  int g = n & 3, u = n >> 2;
  biasv[n] = (g == 0) ? bf_[u] : (g == 1) ? bi_[u] : (g == 2) ? bo_[u] : bc_[u];
}

// 4x4 in-quad transpose via 2 butterfly stages of ds_swizzle (xor1, xor2).
__device__ __forceinline__ void quadtr(f32x4 v, int gg, float& F, float& I, float& O, float& G) {
  const bool o1 = gg & 1, o2 = gg & 2;
  float s01 = o1 ? v[0] : v[1];
  float s23 = o1 ? v[2] : v[3];
  float r01 = __int_as_float(__builtin_amdgcn_ds_swizzle(__float_as_int(s01), 0x041F)); // xor 1
  float r23 = __int_as_float(__builtin_amdgcn_ds_swizzle(__float_as_int(s23), 0x041F));
  float x0 = o1 ? r01 : v[0];
  float x1 = o1 ? v[1] : r01;
  float x2 = o1 ? r23 : v[2];
  float x3 = o1 ? v[3] : r23;
  float s02 = o2 ? x0 : x2;
  float s13 = o2 ? x1 : x3;
  float r02 = __int_as_float(__builtin_amdgcn_ds_swizzle(__float_as_int(s02), 0x081F)); // xor 2
  float r13 = __int_as_float(__builtin_amdgcn_ds_swizzle(__float_as_int(s13), 0x081F));
  F = o2 ? r02 : x0;
  I = o2 ? r13 : x1;
  O = o2 ? x2 : r02;
  G = o2 ? x3 : r13;
}

// ---- persistent recurrence. FINAL (R11 consolidation — session best, 3140 us).
// Structure: 128 WGs x 256 thr; WG owns all 64 batches x 32 gate-cols (8 units);
// weights in LDS + a-chain h-weights hoisted to regs; in-wave quad-transpose
// elementwise (no LDS gate exchange); per-step-unique h buffers (plain cached reads,
// L2-shared per XCD) + atomicExch publish; per-step flag buffers with plain-L2
// detect and sc1 fallback; per-step __syncthreads rendezvous (4x-proven essential:
// keeps flags pre-set at detect, h MALL-fresh, one collective drain);
// x-GEMM split around publish/arrive to cover the drain and flag propagation.
// Floor analysis: step = 6.1us = ~1.3us compute (hidden) + ~4-leg cross-die
// latency chain (publish-drain -> flag -> detect -> h first-touch) x 512 steps,
// with HBM at 2.7% and MFMA at 5.2% — a latency floor, not a roofline.
__global__ __launch_bounds__(256, 1) void lstm_rec(
    const _Float16* __restrict__ xb, const _Float16* __restrict__ WbT,
    const _Float16* __restrict__ WhT, const float* __restrict__ biasv,
    _Float16* __restrict__ hseq, float* __restrict__ out, unsigned* __restrict__ fseq) {
  const int wg = blockIdx.x;           // 0..127
  const int tid = threadIdx.x;
  const int l = tid & 63, w = tid >> 6;
  const int lr = l & 15, lkb = (l >> 4) * 8;
  const int arow = w * 16 + lr;        // batch row this lane supplies to MFMA-A
  const int uu = lr >> 2, gg = l & 3;  // quad id / quad member
  const int u0 = wg * 8 + 2 * uu;      // lane's unit pair (after transpose)
  const int R  = w * 16 + (l >> 4) * 4 + gg;  // lane's batch row (after transpose)

  __shared__ half8 wlds[96 * 64];      // 96 KiB: slot = kk*2+nf; kk<16 -> W_x, else W_h

  for (int idx = tid; idx < 96 * 64; idx += 256) {
    int s = idx >> 6, l2 = idx & 63;
    int kk = s >> 1, nf = s & 1;
    int uu2 = (l2 & 15) >> 2, gg2 = l2 & 3, lkb2 = (l2 >> 4) * 8;
    int col = (wg * 8 + 2 * uu2 + nf) * 4 + gg2;   // interleaved unit assignment
    const _Float16* src = (kk < 16)
      ? WbT + (size_t)col * D_IN + kk * 32 + lkb2
      : WhT + (size_t)col * N_U + (kk - 16) * 32 + lkb2;
    wlds[idx] = *(const half8*)src;
  }

  const float bv0 = biasv[(size_t)u0 * 4 + gg];
  const float bv1 = biasv[(size_t)(u0 + 1) * 4 + gg];
  float c0 = 0.f, c1 = 0.f;

  __syncthreads();                     // wlds ready

  // hoist h-part a-chain W fragments (j=0..15, both col-frags) into regs (R5-proven,
  // NO pin — R12's "+v" pin forced arch-VGPR allocation and cost 70%)
  half8 wh0[16], wh1[16];
#pragma unroll
  for (int j = 0; j < 16; j++) {
    wh0[j] = wlds[((16 + j) * 2 + 0) * 64 + l];
    wh1[j] = wlds[((16 + j) * 2 + 1) * 64 + l];
  }

  // ---- prologue: x-part of step 0 ----
  half8 xfn[16];
  {
    const _Float16* xa = xb + (size_t)arow * D_IN + lkb;
#pragma unroll
    for (int j = 0; j < 16; j++) xfn[j] = *(const half8*)(xa + j * 32);
  }
  f32x4 a0 = {bv0, bv0, bv0, bv0};
  f32x4 a1 = {bv1, bv1, bv1, bv1};
#pragma unroll
  for (int j = 0; j < 16; j++) {
    a0 = __builtin_amdgcn_mfma_f32_16x16x32_f16(xfn[j], wlds[(j * 2 + 0) * 64 + l], a0, 0, 0, 0);
    a1 = __builtin_amdgcn_mfma_f32_16x16x32_f16(xfn[j], wlds[(j * 2 + 1) * 64 + l], a1, 0, 0, 0);
  }

  for (int g = 0; g < T_SEQ; g++) {
    // ---- B: wait until all 128 WGs have published h_g ----
    if (g > 0) {
      unsigned* fg = fseq + (size_t)g * 128;
      if (tid < 128) {
        unsigned v = *((volatile const unsigned*)fg + tid);   // plain cached (L2)
        if (v == 0u) {
          while (__hip_atomic_load(&fg[tid], __ATOMIC_RELAXED, __HIP_MEMORY_SCOPE_AGENT) == 0u)
            __builtin_amdgcn_s_sleep(1);
        }
      }
      asm volatile("" ::: "memory");   // compiler fence: no hoisting of h loads
      __syncthreads();
    }

    // ---- C: h loads (plain, L2-shared) + next-step x loads + 64 h-MFMAs ----
    const _Float16* hp = hseq + (size_t)g * (N_B * N_U) + (size_t)arow * N_U + lkb;
    half8 hf[32];
#pragma unroll
    for (int j = 0; j < 32; j++) hf[j] = *(const half8*)(hp + j * 32);

    const int gn = (g + 1 < T_SEQ) ? g + 1 : 0;
    const _Float16* xa = xb + ((size_t)gn * N_B + arow) * D_IN + lkb;
#pragma unroll
    for (int j = 0; j < 16; j++) xfn[j] = *(const half8*)(xa + j * 32);

    f32x4 b0 = {0.f, 0.f, 0.f, 0.f};
    f32x4 b1 = {0.f, 0.f, 0.f, 0.f};
#pragma unroll
    for (int j = 0; j < 16; j++) {
      a0 = __builtin_amdgcn_mfma_f32_16x16x32_f16(hf[j],      wh0[j], a0, 0, 0, 0);
      a1 = __builtin_amdgcn_mfma_f32_16x16x32_f16(hf[j],      wh1[j], a1, 0, 0, 0);
      b0 = __builtin_amdgcn_mfma_f32_16x16x32_f16(hf[j + 16], wlds[((32 + j) * 2 + 0) * 64 + l], b0, 0, 0, 0);
      b1 = __builtin_amdgcn_mfma_f32_16x16x32_f16(hf[j + 16], wlds[((32 + j) * 2 + 1) * 64 + l], b1, 0, 0, 0);
    }
    a0 += b0;
    a1 += b1;

    // ---- D: in-wave quad transpose + elementwise ----
    float F0, I0, O0, G0, F1, I1, O1, G1;
    quadtr(a0, gg, F0, I0, O0, G0);
    quadtr(a1, gg, F1, I1, O1, G1);
    c0 = sigf(F0) * c0 + sigf(I0) * tanhfast(G0);
    c1 = sigf(F1) * c1 + sigf(I1) * tanhfast(G1);
    float h0v = sigf(O0) * tanhfast(c0);
    float h1v = sigf(O1) * tanhfast(c1);

    // ---- E: publish h_{g+1} — one packed 4B agent atomicExch per lane ----
    unsigned hw;
    { union { _Float16 h[2]; unsigned u; } pk; pk.h[0] = (_Float16)h0v; pk.h[1] = (_Float16)h1v; hw = pk.u; }
    unsigned* hn = (unsigned*)(hseq + (size_t)(g + 1) * (N_B * N_U) + (size_t)R * N_U + u0);
    (void)__hip_atomic_exchange(hn, hw, __ATOMIC_RELAXED, __HIP_MEMORY_SCOPE_AGENT);

    // ---- A1: first half of next step's x-GEMM (covers the publish-ack drain) ----
    a0 = f32x4{bv0, bv0, bv0, bv0};
    a1 = f32x4{bv1, bv1, bv1, bv1};
#pragma unroll
    for (int j = 0; j < 8; j++) {
      a0 = __builtin_amdgcn_mfma_f32_16x16x32_f16(xfn[j], wlds[(j * 2 + 0) * 64 + l], a0, 0, 0, 0);
      a1 = __builtin_amdgcn_mfma_f32_16x16x32_f16(xfn[j], wlds[(j * 2 + 1) * 64 + l], a1, 0, 0, 0);
    }

    // ---- F: arrive — __syncthreads drains vmcnt (h publishes agent-visible) ----
    __syncthreads();
    if (tid == 0)
      (void)__hip_atomic_exchange(&fseq[(size_t)(g + 1) * 128 + wg], 1u, __ATOMIC_RELAXED, __HIP_MEMORY_SCOPE_AGENT);

    // ---- A2: second half of next step's x-GEMM (covers flag propagation) ----
#pragma unroll
    for (int j = 8; j < 16; j++) {
      a0 = __builtin_amdgcn_mfma_f32_16x16x32_f16(xfn[j], wlds[(j * 2 + 0) * 64 + l], a0, 0, 0, 0);
      a1 = __builtin_amdgcn_mfma_f32_16x16x32_f16(xfn[j], wlds[(j * 2 + 1) * 64 + l], a1, 0, 0, 0);
    }

    // ---- G: out store (nt), off the release path ----
    f32x2 ov; ov.x = h0v; ov.y = h1v;
    __builtin_nontemporal_store(ov, (f32x2*)(out + ((size_t)R * T_SEQ + g) * N_U + u0));
  }
}

extern "C" void kernel_launch(void* const* d_in, const int* in_sizes, int n_in,
                              void* d_out, int out_size, void* d_ws, size_t ws_size,
                              hipStream_t stream) {
  const float* x  = (const float*)d_in[0];
  const float* Wf = (const float*)d_in[1];
  const float* Wi = (const float*)d_in[2];
  const float* Wo = (const float*)d_in[3];
  const float* Wc = (const float*)d_in[4];
  const float* bf_ = (const float*)d_in[5];
  const float* bi_ = (const float*)d_in[6];
  const float* bo_ = (const float*)d_in[7];
  const float* bc_ = (const float*)d_in[8];
  float* out = (float*)d_out;

  char* ws = (char*)d_ws;
  _Float16* hseq = (_Float16*)(ws + OFF_HSEQ);
  _Float16* xb   = (_Float16*)(ws + OFF_XB);
  _Float16* WbT  = (_Float16*)(ws + OFF_WBT);
  _Float16* WhT  = (_Float16*)(ws + OFF_WHT);
  float* biasv = (float*)(ws + OFF_BIAS);
  unsigned* fseq = (unsigned*)(ws + OFF_FSEQ);

  (void)hipMemsetAsync(d_ws, 0, 1 << 20, stream);              // hseq[0] (h_0 = zeros)
  (void)hipMemsetAsync(ws + OFF_FSEQ, 0, 513 * 512, stream);   // per-step flags
  pack_x<<<16384, 256, 0, stream>>>(x, xb);
  pack_w<<<6144, 256, 0, stream>>>(Wf, Wi, Wo, Wc, WbT, WhT);
  pack_b<<<16, 256, 0, stream>>>(bf_, bi_, bo_, bc_, biasv);

  lstm_rec<<<128, 256, 0, stream>>>(xb, WbT, WhT, biasv, hseq, out, fseq);
}